// Round 10
// baseline (310.464 us; speedup 1.0000x reference)
//
#include <hip/hip_runtime.h>
#include <hip/hip_cooperative_groups.h>

namespace cg = cooperative_groups;

#define N_NODES 50000
#define N_EDGES 800000
#define IN_C    128
#define HID_C   128
#define OUT_C   64

#define EPB     4096            // edges per block
#define NBLK    196             // grid size of csr_coop; ceil(N_EDGES/EPB)=196
#define NBUCKET 196             // ceil(N_NODES / 256)
#define CAP     6144            // max edges per coarse bucket (mean 4096, sd 64)

typedef unsigned int   uint32;
typedef unsigned short ushort16;
typedef __attribute__((ext_vector_type(8))) short short8;
typedef __attribute__((ext_vector_type(4))) float f32x4;

__device__ __forceinline__ ushort16 f2bf(float f) {
    uint32 u = __float_as_uint(f);
    u += 0x7FFFu + ((u >> 16) & 1u);        // RNE
    return (ushort16)(u >> 16);
}
__device__ __forceinline__ float bf_lo(uint32 h) { return __uint_as_float(h << 16); }
__device__ __forceinline__ float bf_hi(uint32 h) { return __uint_as_float(h & 0xFFFF0000u); }

__device__ __forceinline__ ushort16 f2h_bits(float f) {
    union { _Float16 h; ushort16 u; } cv;
    cv.h = (_Float16)f;
    return cv.u;
}
__device__ __forceinline__ float h_bits2f(uint32 bits) {
    union { ushort16 u; _Float16 h; } cv;
    cv.u = (ushort16)bits;
    return (float)cv.h;
}

// ---------------- MFMA GEMM: C[M,N](bf16) = A[M,128] * W[128,N] --------------
template<int NT, bool ABF16>
__global__ __launch_bounds__(256) void mfma_gemm_kernel(const void* __restrict__ Aptr,
                                                        const ushort16* __restrict__ Wt,
                                                        ushort16* __restrict__ C, int M) {
    constexpr int N = NT * 16;
    __shared__ ushort16 As[64][136];       // +8 pad breaks 16-way bank aliasing
    __shared__ ushort16 Ws[N][136];

    const int tid  = threadIdx.x;
    const int wave = tid >> 6;
    const int lane = tid & 63;
    const int quad = lane >> 4;
    const int m    = lane & 15;
    const int blockRow = blockIdx.x * 64;

#pragma unroll
    for (int p = 0; p < N * 16 / 256; p++) {
        int u = tid + 256 * p;
        int row = u / 16, c8 = u % 16;
        uint4 v = ((const uint4*)Wt)[u];
        *((uint4*)&Ws[row][c8 * 8]) = v;
    }
    if (ABF16) {
#pragma unroll
        for (int p = 0; p < 4; p++) {
            int u = tid + 256 * p;
            int row = u / 16, c8 = u % 16;
            int gr = blockRow + row; if (gr > M - 1) gr = M - 1;
            uint4 v = ((const uint4*)Aptr)[gr * 16 + c8];
            *((uint4*)&As[row][c8 * 8]) = v;
        }
    } else {
#pragma unroll
        for (int p = 0; p < 8; p++) {
            int u = tid + 256 * p;
            int row = u / 32, c4 = u % 32;
            int gr = blockRow + row; if (gr > M - 1) gr = M - 1;
            float4 v = ((const float4*)Aptr)[gr * 32 + c4];
            ushort4 s;
            s.x = f2bf(v.x); s.y = f2bf(v.y); s.z = f2bf(v.z); s.w = f2bf(v.w);
            *((ushort4*)&As[row][c4 * 4]) = s;
        }
    }
    __syncthreads();

    f32x4 acc[NT];
#pragma unroll
    for (int nt = 0; nt < NT; nt++) acc[nt] = (f32x4){0.f, 0.f, 0.f, 0.f};

#pragma unroll
    for (int kc = 0; kc < 128; kc += 32) {
        short8 a = *((const short8*)&As[wave * 16 + m][kc + quad * 8]);
#pragma unroll
        for (int nt = 0; nt < NT; nt++) {
            short8 b = *((const short8*)&Ws[nt * 16 + m][kc + quad * 8]);
            acc[nt] = __builtin_amdgcn_mfma_f32_16x16x32_bf16(a, b, acc[nt], 0, 0, 0);
        }
    }

    __syncthreads();
#pragma unroll
    for (int nt = 0; nt < NT; nt++)
#pragma unroll
        for (int r = 0; r < 4; r++)
            As[wave * 16 + quad * 4 + r][nt * 16 + m] = f2bf(acc[nt][r]);
    __syncthreads();

#pragma unroll
    for (int p = 0; p < 64 * N / 8 / 256; p++) {
        int u = tid + 256 * p;
        int row = u / (N / 8), c8 = u % (N / 8);
        int gr = blockRow + row;
        if (gr < M)
            ((uint4*)C)[gr * (N / 8) + c8] = *((const uint4*)&As[row][c8 * 8]);
    }
}

// ---------------- Fused CSR build (cooperative, 196 blocks x 1024) -----------
// phase 0: W transposes (no sync needed w/ CSR phases)
// phase 1: per-block LDS hist of coarse buckets (dst>>8) -> blockBin[bin][blk]
// phase 2: block 0 scans all 256*NBLK counts -> global exclusive offsets
// phase 3: coarse scatter via LDS cursors (deterministic bases, LDS atomics)
// phase 4: per-bucket fine hist+scan -> rowStart + pairs
__global__ __launch_bounds__(1024) void csr_coop_kernel(
        const int* __restrict__ ei, const float* __restrict__ ew,
        const float* __restrict__ W1, const float* __restrict__ W2,
        ushort16* __restrict__ W1t, ushort16* __restrict__ W2t,
        int* __restrict__ blockBin, int* __restrict__ coarseStart,
        int* __restrict__ rowStart, uint32* __restrict__ key32,
        ushort16* __restrict__ wH, uint32* __restrict__ pairs) {
    __shared__ __align__(16) char smem[38912];
    cg::grid_group grid = cg::this_grid();
    const int t = threadIdx.x, b = blockIdx.x;

    // ---- phase 0: prep W transposes (24576 elems over 200704 threads)
    {
        int g = b * 1024 + t;
        if (g < 128 * 128) {
            int n = g / 128, k = g % 128;
            W1t[g] = f2bf(W1[k * 128 + n]);
        } else if (g < 128 * 128 + 64 * 128) {
            int j = g - 128 * 128;
            int n = j / 128, k = j % 128;
            W2t[j] = f2bf(W2[k * 64 + n]);
        }
    }

    // ---- phase 1: coarse count
    {
        int* hist = (int*)smem;
        if (t < 256) hist[t] = 0;
        __syncthreads();
        int base = b * EPB;
#pragma unroll
        for (int k = 0; k < EPB / 1024; k++) {
            int e = base + t + k * 1024;
            if (e < N_EDGES) atomicAdd(&hist[ei[N_EDGES + e] >> 8], 1);
        }
        __syncthreads();
        if (t < 256) blockBin[t * NBLK + b] = hist[t];
        __syncthreads();
    }
    grid.sync();

    // ---- phase 2: global exclusive scan (block 0 only)
    if (b == 0) {
        int* lds = (int*)smem;
        const int Mtot = 256 * NBLK;        // 50176
        const int C = (Mtot + 1023) / 1024; // 49
        int base = t * C;
        int vals[C];
        int sum = 0;
        for (int k = 0; k < C; k++) {
            int idx = base + k;
            int v = (idx < Mtot) ? blockBin[idx] : 0;
            vals[k] = sum;
            sum += v;
        }
        lds[t] = sum;
        __syncthreads();
        for (int off = 1; off < 1024; off <<= 1) {
            int a = (t >= off) ? lds[t - off] : 0;
            __syncthreads();
            lds[t] += a;
            __syncthreads();
        }
        int tbase = lds[t] - sum;
        for (int k = 0; k < C; k++) {
            int idx = base + k;
            if (idx < Mtot) {
                int ex = tbase + vals[k];
                blockBin[idx] = ex;
                if (idx % NBLK == 0) {
                    int bu = idx / NBLK;
                    if (bu <= NBUCKET) coarseStart[bu] = ex;
                }
            }
        }
        if (t == 0) rowStart[N_NODES] = N_EDGES;
    }
    grid.sync();

    // ---- phase 3: coarse scatter (LDS cursors from scanned bases)
    {
        int* cursor = (int*)smem;
        if (t < 256) cursor[t] = blockBin[t * NBLK + b];
        __syncthreads();
        int base = b * EPB;
#pragma unroll
        for (int k = 0; k < EPB / 1024; k++) {
            int e = base + t + k * 1024;
            if (e < N_EDGES) {
                int dst = ei[N_EDGES + e];
                int src = ei[e];
                float w = ew[e];
                int pos = atomicAdd(&cursor[dst >> 8], 1);   // LDS atomic
                key32[pos] = ((uint32)(dst & 255) << 16) | (uint32)src;
                wH[pos]    = f2h_bits(w);
            }
        }
        __syncthreads();
    }
    grid.sync();

    // ---- phase 4: fine CSR within bucket b (LDS hist+scan over 256 fine bins)
    {
        uint32*   keys  = (uint32*)smem;                 // CAP * 4 = 24576
        ushort16* ws    = (ushort16*)(smem + 24576);     // CAP * 2 = 12288
        int*      hist  = (int*)(smem + 36864);          // 1024
        int*      scan  = (int*)(smem + 37888);          // 1024
        int s = coarseStart[b];
        int len = coarseStart[b + 1] - s;
        if (len > CAP) len = CAP;
        if (t < 256) hist[t] = 0;
        __syncthreads();
        for (int j = t; j < len; j += 1024) {
            uint32 kv = key32[s + j];
            keys[j] = kv;
            ws[j]   = wH[s + j];
            atomicAdd(&hist[kv >> 16], 1);   // LDS atomic
        }
        __syncthreads();
        if (t < 256) scan[t] = hist[t];
        __syncthreads();
        for (int off = 1; off < 256; off <<= 1) {
            int a = 0;
            if (t < 256 && t >= off) a = scan[t - off];
            __syncthreads();
            if (t < 256) scan[t] += a;
            __syncthreads();
        }
        if (t < 256) {
            int excl = scan[t] - hist[t];
            hist[t] = excl;                  // becomes scatter cursor
            int node = b * 256 + t;
            if (node < N_NODES) rowStart[node] = s + excl;
        }
        __syncthreads();
        for (int j = t; j < len; j += 1024) {
            uint32 kv = keys[j];
            int r = atomicAdd(&hist[kv >> 16], 1);   // LDS atomic
            pairs[s + r] = (kv & 0xFFFFu) | ((uint32)ws[j] << 16);
        }
    }
}

// ---------------- Aggregations (wave = node, full-row gather) ----------------
__global__ __launch_bounds__(256) void agg1_kernel(const uint32* __restrict__ H1,
                                                   const int* __restrict__ rowStart,
                                                   const uint32* __restrict__ pairs,
                                                   const float* __restrict__ b1,
                                                   uint32* __restrict__ A1) {
    int node = blockIdx.x * 4 + (threadIdx.x >> 6);
    int lane = threadIdx.x & 63;
    if (node >= N_NODES) return;
    int s = rowStart[node], e = rowStart[node + 1];
    float2 acc = ((const float2*)b1)[lane];
    int i = s;
    for (; i + 8 <= e; i += 8) {
        uint32 p[8], h[8];
#pragma unroll
        for (int j = 0; j < 8; j++) p[j] = pairs[i + j];
#pragma unroll
        for (int j = 0; j < 8; j++) h[j] = H1[(p[j] & 0xFFFFu) * 64 + lane];
#pragma unroll
        for (int j = 0; j < 8; j++) {
            float w = h_bits2f(p[j] >> 16);
            acc.x += w * bf_lo(h[j]);
            acc.y += w * bf_hi(h[j]);
        }
    }
    for (; i < e; i++) {
        uint32 p = pairs[i];
        uint32 h = H1[(p & 0xFFFFu) * 64 + lane];
        float  w = h_bits2f(p >> 16);
        acc.x += w * bf_lo(h);
        acc.y += w * bf_hi(h);
    }
    float rx = fmaxf(acc.x, 0.f), ry = fmaxf(acc.y, 0.f);
    A1[node * 64 + lane] = (uint32)f2bf(rx) | ((uint32)f2bf(ry) << 16);
}

// agg2: out[i](fp32) = b2 + sum_e H2[src_e]; H2 bf16 per lane (64 ch)
__global__ __launch_bounds__(256) void agg2_kernel(const ushort16* __restrict__ H2,
                                                   const int* __restrict__ rowStart,
                                                   const uint32* __restrict__ pairs,
                                                   const float* __restrict__ b2,
                                                   float* __restrict__ out) {
    int node = blockIdx.x * 4 + (threadIdx.x >> 6);
    int lane = threadIdx.x & 63;
    if (node >= N_NODES) return;
    int s = rowStart[node], e = rowStart[node + 1];
    float acc = b2[lane];
    int i = s;
    for (; i + 8 <= e; i += 8) {
        uint32 v[8];
#pragma unroll
        for (int j = 0; j < 8; j++) v[j] = H2[(pairs[i + j] & 0xFFFFu) * 64 + lane];
#pragma unroll
        for (int j = 0; j < 8; j++) acc += __uint_as_float(v[j] << 16);
    }
    for (; i < e; i++) {
        uint32 v = H2[(pairs[i] & 0xFFFFu) * 64 + lane];
        acc += __uint_as_float(v << 16);
    }
    out[node * 64 + lane] = acc;
}

// ---------------- launch -----------------------------------------------------
extern "C" void kernel_launch(void* const* d_in, const int* in_sizes, int n_in,
                              void* d_out, int out_size, void* d_ws, size_t ws_size,
                              hipStream_t stream) {
    const float* x  = (const float*)d_in[0];
    const int*   ei = (const int*)  d_in[1];   // [2, E] int32
    const float* ew = (const float*)d_in[2];
    const float* W1 = (const float*)d_in[3];
    const float* b1 = (const float*)d_in[4];
    const float* W2 = (const float*)d_in[5];
    const float* b2 = (const float*)d_in[6];
    float* out = (float*)d_out;

    // workspace layout (u32 units)
    uint32* H1      = (uint32*)d_ws;                   // 50000*64  (bf16 [N][128])
    uint32* A1      = H1 + (size_t)N_NODES * 64;       // 50000*64  (bf16 [N][128])
    uint32* H2      = A1 + (size_t)N_NODES * 64;       // 50000*32  (bf16 [N][64])
    uint32* pairs   = H2 + (size_t)N_NODES * 32;       // 800000 (src u16 | f16 w)
    uint32* key32   = pairs + N_EDGES;                 // 800000 (fine<<16 | src)
    ushort16* wH    = (ushort16*)(key32 + N_EDGES);    // 800000 u16
    ushort16* W1t   = wH + N_EDGES;                    // 128*128 bf16 transposed
    ushort16* W2t   = W1t + 128 * 128;                 // 64*128 bf16 transposed
    int* blockBin   = (int*)(W2t + 64 * 128);          // 256*NBLK = 50176
    int* coarseStart= blockBin + 256 * NBLK;           // NBUCKET+1
    int* rowStart   = coarseStart + (NBUCKET + 1);     // 50001

    const int gemmBlocks = (N_NODES + 63) / 64;     // 782
    const int nodeBlocks = (N_NODES + 3) / 4;       // 12500

    // CSR build + W transposes, one cooperative kernel
    void* cargs[] = {(void*)&ei, (void*)&ew, (void*)&W1, (void*)&W2,
                     (void*)&W1t, (void*)&W2t, (void*)&blockBin, (void*)&coarseStart,
                     (void*)&rowStart, (void*)&key32, (void*)&wH, (void*)&pairs};
    (void)hipLaunchCooperativeKernel((void*)csr_coop_kernel, dim3(NBLK), dim3(1024),
                                     cargs, 0, stream);

    // H1(bf16) = x @ W1   [MFMA]
    mfma_gemm_kernel<8, false><<<gemmBlocks, 256, 0, stream>>>(x, W1t, (ushort16*)H1, N_NODES);

    // A1(bf16) = relu(segment_sum(w * H1[src]) + b1)
    agg1_kernel<<<nodeBlocks, 256, 0, stream>>>(H1, rowStart, pairs, b1, A1);

    // H2(bf16) = A1 @ W2   [MFMA, bf16 A]
    mfma_gemm_kernel<4, true><<<gemmBlocks, 256, 0, stream>>>(A1, W2t, (ushort16*)H2, N_NODES);

    // out = segment_sum(H2[src]) + b2
    agg2_kernel<<<nodeBlocks, 256, 0, stream>>>((const ushort16*)H2, rowStart, pairs, b2, out);
}

// Round 11
// 231.747 us; speedup vs baseline: 1.3397x; 1.3397x over previous
//
#include <hip/hip_runtime.h>

#define N_NODES 50000
#define N_EDGES 800000
#define IN_C    128
#define HID_C   128
#define OUT_C   64

#define EPB     8192            // edges per count/scatter block
#define NBLK    98              // ceil(N_EDGES / EPB)
#define NBUCKET 196             // ceil(N_NODES / 256)
#define CAP     6144            // max edges per coarse bucket (mean 4082)

typedef unsigned int   uint32;
typedef unsigned short ushort16;
typedef __attribute__((ext_vector_type(8))) short short8;
typedef __attribute__((ext_vector_type(4))) float f32x4;

__device__ __forceinline__ ushort16 f2bf(float f) {
    uint32 u = __float_as_uint(f);
    u += 0x7FFFu + ((u >> 16) & 1u);        // RNE
    return (ushort16)(u >> 16);
}
__device__ __forceinline__ float bf_lo(uint32 h) { return __uint_as_float(h << 16); }
__device__ __forceinline__ float bf_hi(uint32 h) { return __uint_as_float(h & 0xFFFF0000u); }

__device__ __forceinline__ ushort16 f2h_bits(float f) {
    union { _Float16 h; ushort16 u; } cv;
    cv.h = (_Float16)f;
    return cv.u;
}
__device__ __forceinline__ float h_bits2f(uint32 bits) {
    union { ushort16 u; _Float16 h; } cv;
    cv.u = (ushort16)bits;
    return (float)cv.h;
}

// ---------------- MFMA GEMM (+optional fused coarse count) -------------------
// C[M,N](bf16) = A[M,128] * W[128,N].  W is RAW fp32 [128][N]; transpose+cast
// to bf16 happens during LDS staging (once per block).
// Blocks [0, gemmBlocks) do GEMM; blocks >= gemmBlocks do the CSR coarse
// histogram (256 thr, EPB edges each) when FUSECOUNT.
template<int NT, bool ABF16, bool FUSECOUNT>
__global__ __launch_bounds__(256) void gemm_count_kernel(
        const void* __restrict__ Aptr, const float* __restrict__ W,
        ushort16* __restrict__ C, int M, int gemmBlocks,
        const int* __restrict__ ei, int* __restrict__ blockBin) {
    constexpr int N = NT * 16;
    __shared__ ushort16 As[64][136];       // +8 pad breaks 16-way bank aliasing
    __shared__ ushort16 Ws[N][136];
    __shared__ int hist[256];

    const int tid = threadIdx.x;

    if (FUSECOUNT && (int)blockIdx.x >= gemmBlocks) {
        int blk = blockIdx.x - gemmBlocks;
        hist[tid] = 0;
        __syncthreads();
        int base = blk * EPB;
#pragma unroll
        for (int k = 0; k < EPB / 256; k++) {
            int e = base + tid + k * 256;
            if (e < N_EDGES) atomicAdd(&hist[ei[N_EDGES + e] >> 8], 1);
        }
        __syncthreads();
        blockBin[tid * NBLK + blk] = hist[tid];
        return;
    }

    const int wave = tid >> 6;
    const int lane = tid & 63;
    const int quad = lane >> 4;
    const int m    = lane & 15;
    const int blockRow = blockIdx.x * 64;

    // stage W (fp32 [128][N]) -> Ws[n][k] bf16 transposed
#pragma unroll
    for (int p = 0; p < 128 * N / 256; p++) {
        int u = tid + 256 * p;
        int k = u / N, n = u % N;
        Ws[n][k] = f2bf(W[u]);
    }
    // stage A
    if (ABF16) {
#pragma unroll
        for (int p = 0; p < 4; p++) {
            int u = tid + 256 * p;
            int row = u / 16, c8 = u % 16;
            int gr = blockRow + row; if (gr > M - 1) gr = M - 1;
            uint4 v = ((const uint4*)Aptr)[gr * 16 + c8];
            *((uint4*)&As[row][c8 * 8]) = v;
        }
    } else {
#pragma unroll
        for (int p = 0; p < 8; p++) {
            int u = tid + 256 * p;
            int row = u / 32, c4 = u % 32;
            int gr = blockRow + row; if (gr > M - 1) gr = M - 1;
            float4 v = ((const float4*)Aptr)[gr * 32 + c4];
            ushort4 s;
            s.x = f2bf(v.x); s.y = f2bf(v.y); s.z = f2bf(v.z); s.w = f2bf(v.w);
            *((ushort4*)&As[row][c4 * 4]) = s;
        }
    }
    __syncthreads();

    f32x4 acc[NT];
#pragma unroll
    for (int nt = 0; nt < NT; nt++) acc[nt] = (f32x4){0.f, 0.f, 0.f, 0.f};

#pragma unroll
    for (int kc = 0; kc < 128; kc += 32) {
        short8 a = *((const short8*)&As[wave * 16 + m][kc + quad * 8]);
#pragma unroll
        for (int nt = 0; nt < NT; nt++) {
            short8 b = *((const short8*)&Ws[nt * 16 + m][kc + quad * 8]);
            acc[nt] = __builtin_amdgcn_mfma_f32_16x16x32_bf16(a, b, acc[nt], 0, 0, 0);
        }
    }

    // epilogue: regs -> LDS (bf16) -> coalesced 16B stores
    __syncthreads();
#pragma unroll
    for (int nt = 0; nt < NT; nt++)
#pragma unroll
        for (int r = 0; r < 4; r++)
            As[wave * 16 + quad * 4 + r][nt * 16 + m] = f2bf(acc[nt][r]);
    __syncthreads();

#pragma unroll
    for (int p = 0; p < 64 * N / 8 / 256; p++) {
        int u = tid + 256 * p;
        int row = u / (N / 8), c8 = u % (N / 8);
        int gr = blockRow + row;
        if (gr < M)
            ((uint4*)C)[gr * (N / 8) + c8] = *((const uint4*)&As[row][c8 * 8]);
    }
}

// ---------------- CSR build (counting sort, no per-edge global atomics) ------
__global__ __launch_bounds__(1024) void csr_scan_kernel(int* __restrict__ blockBin,
                                                        int* __restrict__ coarseStart,
                                                        int* __restrict__ rowStart) {
    __shared__ int lds[1024];
    const int Mtot = 256 * NBLK;            // 25088
    const int C = (Mtot + 1023) / 1024;     // 25
    int t = threadIdx.x;
    int base = t * C;
    int vals[C];
    int sum = 0;
    for (int k = 0; k < C; k++) {
        int idx = base + k;
        int v = (idx < Mtot) ? blockBin[idx] : 0;
        vals[k] = sum;
        sum += v;
    }
    lds[t] = sum;
    __syncthreads();
    for (int off = 1; off < 1024; off <<= 1) {
        int a = (t >= off) ? lds[t - off] : 0;
        __syncthreads();
        lds[t] += a;
        __syncthreads();
    }
    int tbase = lds[t] - sum;
    for (int k = 0; k < C; k++) {
        int idx = base + k;
        if (idx < Mtot) {
            int ex = tbase + vals[k];
            blockBin[idx] = ex;
            if (idx % NBLK == 0) {
                int b = idx / NBLK;
                if (b < NBUCKET) coarseStart[b] = ex;
            }
        }
    }
    if (t == 0) { coarseStart[NBUCKET] = N_EDGES; rowStart[N_NODES] = N_EDGES; }
}

__global__ __launch_bounds__(1024) void csr_scatter1_kernel(const int* __restrict__ ei,
                                                            const float* __restrict__ ew,
                                                            const int* __restrict__ blockBin,
                                                            uint32* __restrict__ key32,
                                                            ushort16* __restrict__ wH) {
    __shared__ int cursor[256];
    int t = threadIdx.x, blk = blockIdx.x;
    if (t < 256) cursor[t] = blockBin[t * NBLK + blk];
    __syncthreads();
    int base = blk * EPB;
#pragma unroll
    for (int k = 0; k < EPB / 1024; k++) {
        int e = base + t + k * 1024;
        if (e < N_EDGES) {
            int dst = ei[N_EDGES + e];
            int src = ei[e];
            float w = ew[e];
            int pos = atomicAdd(&cursor[dst >> 8], 1);   // LDS atomic
            key32[pos] = ((uint32)(dst & 255) << 16) | (uint32)src;
            wH[pos]    = f2h_bits(w);
        }
    }
}

__global__ __launch_bounds__(1024) void csr_fine_kernel(const uint32* __restrict__ key32,
                                                        const ushort16* __restrict__ wH,
                                                        const int* __restrict__ coarseStart,
                                                        int* __restrict__ rowStart,
                                                        uint32* __restrict__ pairs) {
    __shared__ uint32   keys[CAP];
    __shared__ ushort16 ws[CAP];
    __shared__ int hist[256];
    __shared__ int scan[256];
    int b = blockIdx.x, t = threadIdx.x;
    int s = coarseStart[b];
    int len = coarseStart[b + 1] - s;
    if (len > CAP) len = CAP;
    if (t < 256) hist[t] = 0;
    __syncthreads();
    for (int j = t; j < len; j += 1024) {
        uint32 kv = key32[s + j];
        keys[j] = kv;
        ws[j]   = wH[s + j];
        atomicAdd(&hist[kv >> 16], 1);   // LDS atomic
    }
    __syncthreads();
    if (t < 256) scan[t] = hist[t];
    __syncthreads();
    for (int off = 1; off < 256; off <<= 1) {
        int a = 0;
        if (t < 256 && t >= off) a = scan[t - off];
        __syncthreads();
        if (t < 256) scan[t] += a;
        __syncthreads();
    }
    if (t < 256) {
        int excl = scan[t] - hist[t];
        hist[t] = excl;                  // becomes scatter cursor
        int node = b * 256 + t;
        if (node < N_NODES) rowStart[node] = s + excl;
    }
    __syncthreads();
    for (int j = t; j < len; j += 1024) {
        uint32 kv = keys[j];
        int r = atomicAdd(&hist[kv >> 16], 1);   // LDS atomic
        pairs[s + r] = (kv & 0xFFFFu) | ((uint32)ws[j] << 16);
    }
}

// ---------------- Aggregations (wave = node, full-row gather) ----------------
__global__ __launch_bounds__(256) void agg1_kernel(const uint32* __restrict__ H1,
                                                   const int* __restrict__ rowStart,
                                                   const uint32* __restrict__ pairs,
                                                   const float* __restrict__ b1,
                                                   uint32* __restrict__ A1) {
    int node = blockIdx.x * 4 + (threadIdx.x >> 6);
    int lane = threadIdx.x & 63;
    if (node >= N_NODES) return;
    int s = rowStart[node], e = rowStart[node + 1];
    float2 acc = ((const float2*)b1)[lane];
    int i = s;
    for (; i + 8 <= e; i += 8) {
        uint32 p[8], h[8];
#pragma unroll
        for (int j = 0; j < 8; j++) p[j] = pairs[i + j];
#pragma unroll
        for (int j = 0; j < 8; j++) h[j] = H1[(p[j] & 0xFFFFu) * 64 + lane];
#pragma unroll
        for (int j = 0; j < 8; j++) {
            float w = h_bits2f(p[j] >> 16);
            acc.x += w * bf_lo(h[j]);
            acc.y += w * bf_hi(h[j]);
        }
    }
    for (; i < e; i++) {
        uint32 p = pairs[i];
        uint32 h = H1[(p & 0xFFFFu) * 64 + lane];
        float  w = h_bits2f(p >> 16);
        acc.x += w * bf_lo(h);
        acc.y += w * bf_hi(h);
    }
    float rx = fmaxf(acc.x, 0.f), ry = fmaxf(acc.y, 0.f);
    A1[node * 64 + lane] = (uint32)f2bf(rx) | ((uint32)f2bf(ry) << 16);
}

__global__ __launch_bounds__(256) void agg2_kernel(const ushort16* __restrict__ H2,
                                                   const int* __restrict__ rowStart,
                                                   const uint32* __restrict__ pairs,
                                                   const float* __restrict__ b2,
                                                   float* __restrict__ out) {
    int node = blockIdx.x * 4 + (threadIdx.x >> 6);
    int lane = threadIdx.x & 63;
    if (node >= N_NODES) return;
    int s = rowStart[node], e = rowStart[node + 1];
    float acc = b2[lane];
    int i = s;
    for (; i + 8 <= e; i += 8) {
        uint32 v[8];
#pragma unroll
        for (int j = 0; j < 8; j++) v[j] = H2[(pairs[i + j] & 0xFFFFu) * 64 + lane];
#pragma unroll
        for (int j = 0; j < 8; j++) acc += __uint_as_float(v[j] << 16);
    }
    for (; i < e; i++) {
        uint32 v = H2[(pairs[i] & 0xFFFFu) * 64 + lane];
        acc += __uint_as_float(v << 16);
    }
    out[node * 64 + lane] = acc;
}

// ---------------- launch -----------------------------------------------------
extern "C" void kernel_launch(void* const* d_in, const int* in_sizes, int n_in,
                              void* d_out, int out_size, void* d_ws, size_t ws_size,
                              hipStream_t stream) {
    const float* x  = (const float*)d_in[0];
    const int*   ei = (const int*)  d_in[1];   // [2, E] int32
    const float* ew = (const float*)d_in[2];
    const float* W1 = (const float*)d_in[3];
    const float* b1 = (const float*)d_in[4];
    const float* W2 = (const float*)d_in[5];
    const float* b2 = (const float*)d_in[6];
    float* out = (float*)d_out;

    // workspace layout (u32 units)
    uint32* H1      = (uint32*)d_ws;                   // 50000*64  (bf16 [N][128])
    uint32* A1      = H1 + (size_t)N_NODES * 64;       // 50000*64  (bf16 [N][128])
    uint32* H2      = A1 + (size_t)N_NODES * 64;       // 50000*32  (bf16 [N][64])
    uint32* pairs   = H2 + (size_t)N_NODES * 32;       // 800000 (src u16 | f16 w)
    uint32* key32   = pairs + N_EDGES;                 // 800000 (fine<<16 | src)
    ushort16* wH    = (ushort16*)(key32 + N_EDGES);    // 800000 u16
    int* blockBin   = (int*)(wH + N_EDGES);            // 256*NBLK = 25088
    int* coarseStart= blockBin + 256 * NBLK;           // NBUCKET+1
    int* rowStart   = coarseStart + (NBUCKET + 1);     // 50001

    const int gemmBlocks = (N_NODES + 63) / 64;     // 782
    const int nodeBlocks = (N_NODES + 3) / 4;       // 12500

    // H1(bf16) = x @ W1 [MFMA] + fused CSR coarse count (independent work)
    gemm_count_kernel<8, false, true><<<gemmBlocks + NBLK, 256, 0, stream>>>(
        x, W1, (ushort16*)H1, N_NODES, gemmBlocks, ei, blockBin);

    // scan -> coarse scatter -> fine CSR
    csr_scan_kernel<<<1, 1024, 0, stream>>>(blockBin, coarseStart, rowStart);
    csr_scatter1_kernel<<<NBLK, 1024, 0, stream>>>(ei, ew, blockBin, key32, wH);
    csr_fine_kernel<<<NBUCKET, 1024, 0, stream>>>(key32, wH, coarseStart, rowStart, pairs);

    // A1(bf16) = relu(segment_sum(w * H1[src]) + b1)
    agg1_kernel<<<nodeBlocks, 256, 0, stream>>>(H1, rowStart, pairs, b1, A1);

    // H2(bf16) = A1 @ W2 [MFMA]
    gemm_count_kernel<4, true, false><<<gemmBlocks, 256, 0, stream>>>(
        A1, W2, (ushort16*)H2, N_NODES, gemmBlocks, ei, blockBin);

    // out = segment_sum(H2[src]) + b2
    agg2_kernel<<<nodeBlocks, 256, 0, stream>>>((const ushort16*)H2, rowStart, pairs, b2, out);
}

// Round 12
// 217.235 us; speedup vs baseline: 1.4292x; 1.0668x over previous
//
#include <hip/hip_runtime.h>

#define N_NODES 50000
#define N_EDGES 800000
#define IN_C    128
#define HID_C   128
#define OUT_C   64

#define EPB     8192            // edges per block (count/scatter)
#define NBLK    98              // ceil(N_EDGES / EPB)
#define NBUCKET 196             // ceil(N_NODES / 256)
#define CAP     6144            // max edges per coarse bucket (mean 4082)

typedef unsigned int   uint32;
typedef unsigned short ushort16;
typedef __attribute__((ext_vector_type(8))) short short8;
typedef __attribute__((ext_vector_type(4))) float f32x4;

__device__ __forceinline__ ushort16 f2bf(float f) {
    uint32 u = __float_as_uint(f);
    u += 0x7FFFu + ((u >> 16) & 1u);        // RNE
    return (ushort16)(u >> 16);
}
__device__ __forceinline__ float bf_lo(uint32 h) { return __uint_as_float(h << 16); }
__device__ __forceinline__ float bf_hi(uint32 h) { return __uint_as_float(h & 0xFFFF0000u); }

__device__ __forceinline__ ushort16 f2h_bits(float f) {
    union { _Float16 h; ushort16 u; } cv;
    cv.h = (_Float16)f;
    return cv.u;
}
__device__ __forceinline__ float h_bits2f(uint32 bits) {
    union { ushort16 u; _Float16 h; } cv;
    cv.u = (ushort16)bits;
    return (float)cv.h;
}

// ---------------- W pre-transpose: Wt[n][k] = bf16(W[k][n]) ------------------
__global__ void prep_w_kernel(const float* __restrict__ W1, const float* __restrict__ W2,
                              ushort16* __restrict__ W1t, ushort16* __restrict__ W2t) {
    int i = blockIdx.x * 256 + threadIdx.x;
    if (i < 128 * 128) {
        int n = i / 128, k = i % 128;
        W1t[i] = f2bf(W1[k * 128 + n]);
    }
    int j = i - 128 * 128;
    if (j >= 0 && j < 64 * 128) {
        int n = j / 128, k = j % 128;
        W2t[j] = f2bf(W2[k * 64 + n]);
    }
}

// ---------------- MFMA GEMM: C[M,N](bf16) = A[M,128] * W[128,N] --------------
template<int NT, bool ABF16>
__global__ __launch_bounds__(256) void mfma_gemm_kernel(const void* __restrict__ Aptr,
                                                        const ushort16* __restrict__ Wt,
                                                        ushort16* __restrict__ C, int M) {
    constexpr int N = NT * 16;
    __shared__ ushort16 As[64][136];       // +8 pad breaks 16-way bank aliasing
    __shared__ ushort16 Ws[N][136];

    const int tid  = threadIdx.x;
    const int wave = tid >> 6;
    const int lane = tid & 63;
    const int quad = lane >> 4;
    const int m    = lane & 15;
    const int blockRow = blockIdx.x * 64;

#pragma unroll
    for (int p = 0; p < N * 16 / 256; p++) {
        int u = tid + 256 * p;
        int row = u / 16, c8 = u % 16;
        uint4 v = ((const uint4*)Wt)[u];
        *((uint4*)&Ws[row][c8 * 8]) = v;
    }
    if (ABF16) {
#pragma unroll
        for (int p = 0; p < 4; p++) {
            int u = tid + 256 * p;
            int row = u / 16, c8 = u % 16;
            int gr = blockRow + row; if (gr > M - 1) gr = M - 1;
            uint4 v = ((const uint4*)Aptr)[gr * 16 + c8];
            *((uint4*)&As[row][c8 * 8]) = v;
        }
    } else {
#pragma unroll
        for (int p = 0; p < 8; p++) {
            int u = tid + 256 * p;
            int row = u / 32, c4 = u % 32;
            int gr = blockRow + row; if (gr > M - 1) gr = M - 1;
            float4 v = ((const float4*)Aptr)[gr * 32 + c4];
            ushort4 s;
            s.x = f2bf(v.x); s.y = f2bf(v.y); s.z = f2bf(v.z); s.w = f2bf(v.w);
            *((ushort4*)&As[row][c4 * 4]) = s;
        }
    }
    __syncthreads();

    f32x4 acc[NT];
#pragma unroll
    for (int nt = 0; nt < NT; nt++) acc[nt] = (f32x4){0.f, 0.f, 0.f, 0.f};

#pragma unroll
    for (int kc = 0; kc < 128; kc += 32) {
        short8 a = *((const short8*)&As[wave * 16 + m][kc + quad * 8]);
#pragma unroll
        for (int nt = 0; nt < NT; nt++) {
            short8 b = *((const short8*)&Ws[nt * 16 + m][kc + quad * 8]);
            acc[nt] = __builtin_amdgcn_mfma_f32_16x16x32_bf16(a, b, acc[nt], 0, 0, 0);
        }
    }

    __syncthreads();
#pragma unroll
    for (int nt = 0; nt < NT; nt++)
#pragma unroll
        for (int r = 0; r < 4; r++)
            As[wave * 16 + quad * 4 + r][nt * 16 + m] = f2bf(acc[nt][r]);
    __syncthreads();

#pragma unroll
    for (int p = 0; p < 64 * N / 8 / 256; p++) {
        int u = tid + 256 * p;
        int row = u / (N / 8), c8 = u % (N / 8);
        int gr = blockRow + row;
        if (gr < M)
            ((uint4*)C)[gr * (N / 8) + c8] = *((const uint4*)&As[row][c8 * 8]);
    }
}

// ---------------- CSR build: 2-level counting sort, zero per-edge global atomics
__global__ __launch_bounds__(1024) void csr_count_kernel(const int* __restrict__ ei,
                                                         int* __restrict__ blockBin) {
    __shared__ int hist[256];
    int t = threadIdx.x, blk = blockIdx.x;
    if (t < 256) hist[t] = 0;
    __syncthreads();
    int base = blk * EPB;
#pragma unroll
    for (int k = 0; k < EPB / 1024; k++) {
        int e = base + t + k * 1024;
        if (e < N_EDGES) atomicAdd(&hist[ei[N_EDGES + e] >> 8], 1);
    }
    __syncthreads();
    if (t < 256) blockBin[t * NBLK + blk] = hist[t];
}

__global__ __launch_bounds__(1024) void csr_scan_kernel(int* __restrict__ blockBin,
                                                        int* __restrict__ coarseStart,
                                                        int* __restrict__ rowStart) {
    __shared__ int lds[1024];
    const int Mtot = 256 * NBLK;            // 25088
    const int C = (Mtot + 1023) / 1024;     // 25
    int t = threadIdx.x;
    int base = t * C;
    int vals[C];
    int sum = 0;
    for (int k = 0; k < C; k++) {
        int idx = base + k;
        int v = (idx < Mtot) ? blockBin[idx] : 0;
        vals[k] = sum;
        sum += v;
    }
    lds[t] = sum;
    __syncthreads();
    for (int off = 1; off < 1024; off <<= 1) {
        int a = (t >= off) ? lds[t - off] : 0;
        __syncthreads();
        lds[t] += a;
        __syncthreads();
    }
    int tbase = lds[t] - sum;
    for (int k = 0; k < C; k++) {
        int idx = base + k;
        if (idx < Mtot) {
            int ex = tbase + vals[k];
            blockBin[idx] = ex;
            if (idx % NBLK == 0) {
                int b = idx / NBLK;
                if (b < NBUCKET) coarseStart[b] = ex;
            }
        }
    }
    if (t == 0) { coarseStart[NBUCKET] = N_EDGES; rowStart[N_NODES] = N_EDGES; }
}

__global__ __launch_bounds__(1024) void csr_scatter1_kernel(const int* __restrict__ ei,
                                                            const float* __restrict__ ew,
                                                            const int* __restrict__ blockBin,
                                                            uint32* __restrict__ key32,
                                                            ushort16* __restrict__ wH) {
    __shared__ int cursor[256];
    int t = threadIdx.x, blk = blockIdx.x;
    if (t < 256) cursor[t] = blockBin[t * NBLK + blk];
    __syncthreads();
    int base = blk * EPB;
#pragma unroll
    for (int k = 0; k < EPB / 1024; k++) {
        int e = base + t + k * 1024;
        if (e < N_EDGES) {
            int dst = ei[N_EDGES + e];
            int src = ei[e];
            float w = ew[e];
            int pos = atomicAdd(&cursor[dst >> 8], 1);   // LDS atomic
            key32[pos] = ((uint32)(dst & 255) << 16) | (uint32)src;
            wH[pos]    = f2h_bits(w);
        }
    }
}

__global__ __launch_bounds__(1024) void csr_fine_kernel(const uint32* __restrict__ key32,
                                                        const ushort16* __restrict__ wH,
                                                        const int* __restrict__ coarseStart,
                                                        int* __restrict__ rowStart,
                                                        uint32* __restrict__ pairs) {
    __shared__ uint32   keys[CAP];
    __shared__ ushort16 ws[CAP];
    __shared__ int hist[256];
    __shared__ int scan[256];
    int b = blockIdx.x, t = threadIdx.x;
    int s = coarseStart[b];
    int len = coarseStart[b + 1] - s;
    if (len > CAP) len = CAP;
    if (t < 256) hist[t] = 0;
    __syncthreads();
    for (int j = t; j < len; j += 1024) {
        uint32 kv = key32[s + j];
        keys[j] = kv;
        ws[j]   = wH[s + j];
        atomicAdd(&hist[kv >> 16], 1);   // LDS atomic
    }
    __syncthreads();
    if (t < 256) scan[t] = hist[t];
    __syncthreads();
    for (int off = 1; off < 256; off <<= 1) {
        int a = 0;
        if (t < 256 && t >= off) a = scan[t - off];
        __syncthreads();
        if (t < 256) scan[t] += a;
        __syncthreads();
    }
    if (t < 256) {
        int excl = scan[t] - hist[t];
        hist[t] = excl;                  // becomes the scatter cursor
        int node = b * 256 + t;
        if (node < N_NODES) rowStart[node] = s + excl;
    }
    __syncthreads();
    for (int j = t; j < len; j += 1024) {
        uint32 kv = keys[j];
        int r = atomicAdd(&hist[kv >> 16], 1);   // LDS atomic
        pairs[s + r] = (kv & 0xFFFFu) | ((uint32)ws[j] << 16);
    }
}

// ---------------- Aggregations (wave = node, 16-deep gather pipeline) --------
__global__ __launch_bounds__(256) void agg1_kernel(const uint32* __restrict__ H1,
                                                   const int* __restrict__ rowStart,
                                                   const uint32* __restrict__ pairs,
                                                   const float* __restrict__ b1,
                                                   uint32* __restrict__ A1) {
    int node = blockIdx.x * 4 + (threadIdx.x >> 6);
    int lane = threadIdx.x & 63;
    if (node >= N_NODES) return;
    int s = rowStart[node], e = rowStart[node + 1];
    float2 acc = ((const float2*)b1)[lane];
    int i = s;
    for (; i + 16 <= e; i += 16) {
        uint32 p[16], h[16];
#pragma unroll
        for (int j = 0; j < 16; j++) p[j] = pairs[i + j];
#pragma unroll
        for (int j = 0; j < 16; j++) h[j] = H1[(p[j] & 0xFFFFu) * 64 + lane];
#pragma unroll
        for (int j = 0; j < 16; j++) {
            float w = h_bits2f(p[j] >> 16);
            acc.x += w * bf_lo(h[j]);
            acc.y += w * bf_hi(h[j]);
        }
    }
    for (; i + 8 <= e; i += 8) {
        uint32 p[8], h[8];
#pragma unroll
        for (int j = 0; j < 8; j++) p[j] = pairs[i + j];
#pragma unroll
        for (int j = 0; j < 8; j++) h[j] = H1[(p[j] & 0xFFFFu) * 64 + lane];
#pragma unroll
        for (int j = 0; j < 8; j++) {
            float w = h_bits2f(p[j] >> 16);
            acc.x += w * bf_lo(h[j]);
            acc.y += w * bf_hi(h[j]);
        }
    }
    for (; i < e; i++) {
        uint32 p = pairs[i];
        uint32 h = H1[(p & 0xFFFFu) * 64 + lane];
        float  w = h_bits2f(p >> 16);
        acc.x += w * bf_lo(h);
        acc.y += w * bf_hi(h);
    }
    float rx = fmaxf(acc.x, 0.f), ry = fmaxf(acc.y, 0.f);
    A1[node * 64 + lane] = (uint32)f2bf(rx) | ((uint32)f2bf(ry) << 16);
}

__global__ __launch_bounds__(256) void agg2_kernel(const ushort16* __restrict__ H2,
                                                   const int* __restrict__ rowStart,
                                                   const uint32* __restrict__ pairs,
                                                   const float* __restrict__ b2,
                                                   float* __restrict__ out) {
    int node = blockIdx.x * 4 + (threadIdx.x >> 6);
    int lane = threadIdx.x & 63;
    if (node >= N_NODES) return;
    int s = rowStart[node], e = rowStart[node + 1];
    float acc = b2[lane];
    int i = s;
    for (; i + 16 <= e; i += 16) {
        uint32 v[16];
#pragma unroll
        for (int j = 0; j < 16; j++) v[j] = H2[(pairs[i + j] & 0xFFFFu) * 64 + lane];
#pragma unroll
        for (int j = 0; j < 16; j++) acc += __uint_as_float(v[j] << 16);
    }
    for (; i + 8 <= e; i += 8) {
        uint32 v[8];
#pragma unroll
        for (int j = 0; j < 8; j++) v[j] = H2[(pairs[i + j] & 0xFFFFu) * 64 + lane];
#pragma unroll
        for (int j = 0; j < 8; j++) acc += __uint_as_float(v[j] << 16);
    }
    for (; i < e; i++) {
        uint32 v = H2[(pairs[i] & 0xFFFFu) * 64 + lane];
        acc += __uint_as_float(v << 16);
    }
    out[node * 64 + lane] = acc;
}

// ---------------- launch -----------------------------------------------------
extern "C" void kernel_launch(void* const* d_in, const int* in_sizes, int n_in,
                              void* d_out, int out_size, void* d_ws, size_t ws_size,
                              hipStream_t stream) {
    const float* x  = (const float*)d_in[0];
    const int*   ei = (const int*)  d_in[1];   // [2, E] int32
    const float* ew = (const float*)d_in[2];
    const float* W1 = (const float*)d_in[3];
    const float* b1 = (const float*)d_in[4];
    const float* W2 = (const float*)d_in[5];
    const float* b2 = (const float*)d_in[6];
    float* out = (float*)d_out;

    // workspace layout (u32 units)
    uint32* H1      = (uint32*)d_ws;                   // 50000*64  (bf16 [N][128])
    uint32* A1      = H1 + (size_t)N_NODES * 64;       // 50000*64  (bf16 [N][128])
    uint32* H2      = A1 + (size_t)N_NODES * 64;       // 50000*32  (bf16 [N][64])
    uint32* pairs   = H2 + (size_t)N_NODES * 32;       // 800000 (src u16 | f16 w)
    uint32* key32   = pairs + N_EDGES;                 // 800000 (fine<<16 | src)
    ushort16* wH    = (ushort16*)(key32 + N_EDGES);    // 800000 u16
    ushort16* W1t   = wH + N_EDGES;                    // 128*128 bf16 transposed
    ushort16* W2t   = W1t + 128 * 128;                 // 64*128 bf16 transposed
    int* blockBin   = (int*)(W2t + 64 * 128);          // 256*NBLK = 25088
    int* coarseStart= blockBin + 256 * NBLK;           // NBUCKET+1
    int* rowStart   = coarseStart + (NBUCKET + 1);     // 50001

    const int gemmBlocks = (N_NODES + 63) / 64;     // 782
    const int nodeBlocks = (N_NODES + 3) / 4;       // 12500

    // W transposes (bf16)
    prep_w_kernel<<<96, 256, 0, stream>>>(W1, W2, W1t, W2t);

    // H1(bf16) = x @ W1   [MFMA]
    mfma_gemm_kernel<8, false><<<gemmBlocks, 256, 0, stream>>>(x, W1t, (ushort16*)H1, N_NODES);

    // CSR build: counting sort, no per-edge global atomics
    csr_count_kernel<<<NBLK, 1024, 0, stream>>>(ei, blockBin);
    csr_scan_kernel<<<1, 1024, 0, stream>>>(blockBin, coarseStart, rowStart);
    csr_scatter1_kernel<<<NBLK, 1024, 0, stream>>>(ei, ew, blockBin, key32, wH);
    csr_fine_kernel<<<NBUCKET, 1024, 0, stream>>>(key32, wH, coarseStart, rowStart, pairs);

    // A1(bf16) = relu(segment_sum(w * H1[src]) + b1)
    agg1_kernel<<<nodeBlocks, 256, 0, stream>>>(H1, rowStart, pairs, b1, A1);

    // H2(bf16) = A1 @ W2   [MFMA, bf16 A]
    mfma_gemm_kernel<4, true><<<gemmBlocks, 256, 0, stream>>>(A1, W2t, (ushort16*)H2, N_NODES);

    // out = segment_sum(H2[src]) + b2
    agg2_kernel<<<nodeBlocks, 256, 0, stream>>>((const ushort16*)H2, rowStart, pairs, b2, out);
}